// Round 1
// baseline (523.152 us; speedup 1.0000x reference)
//
#include <hip/hip_runtime.h>

// FilteredPatchLoss: B=64, H=W=1024, p=16.
// Stripe = (b, ih): 16 rows x 1024 cols = 16384 floats, 64 patches per stripe.
// One 256-thread block per stripe; thread t owns patch t/4 across all rows
// (since flat float4 idx f = k*256 + t gives patch = (f&255)>>2 = t>>2).

#define PATCH 16
#define WIDTH 1024

__global__ __launch_bounds__(256) void patch_loss_kernel(
    const float* __restrict__ outp, const float* __restrict__ tgtp,
    const int* __restrict__ filter_rate_p, float* __restrict__ ws)
{
    const int t = threadIdx.x;
    const long long base = (long long)blockIdx.x * (PATCH * WIDTH);
    const float4* op = (const float4*)(outp + base);
    const float4* tp = (const float4*)(tgtp + base);

    float ts = 0.f, ls = 0.f;
#pragma unroll
    for (int k = 0; k < 16; ++k) {
        float4 o = op[k * 256 + t];
        float4 g = tp[k * 256 + t];
        ts += (g.x + g.y) + (g.z + g.w);
        ls += (fabsf(o.x - g.x) + fabsf(o.y - g.y)) +
              (fabsf(o.z - g.z) + fabsf(o.w - g.w));
    }

    __shared__ float s_t[256];
    __shared__ float s_l[256];
    s_t[t] = ts;
    s_l[t] = ls;
    __syncthreads();

    if (t < 64) {  // exactly wave 0
        float tsum = (s_t[4*t] + s_t[4*t+1]) + (s_t[4*t+2] + s_t[4*t+3]);
        float lsum = (s_l[4*t] + s_l[4*t+1]) + (s_l[4*t+2] + s_l[4*t+3]);
        const float fr = (float)(*filter_rate_p);
        const bool mask = (tsum * (1.0f / 256.0f)) > fr;
        float loss = mask ? lsum * (1.0f / 256.0f) : 0.0f;
        float cnt  = mask ? 1.0f : 0.0f;
#pragma unroll
        for (int off = 32; off >= 1; off >>= 1) {
            loss += __shfl_down(loss, off, 64);
            cnt  += __shfl_down(cnt,  off, 64);
        }
        if (t == 0) {
            atomicAdd(&ws[0], loss);
            atomicAdd(&ws[1], cnt);
        }
    }
}

__global__ void finalize_kernel(const float* __restrict__ ws,
                                float* __restrict__ out)
{
    out[0] = ws[0] / ws[1];
}

extern "C" void kernel_launch(void* const* d_in, const int* in_sizes, int n_in,
                              void* d_out, int out_size, void* d_ws, size_t ws_size,
                              hipStream_t stream)
{
    const float* outp = (const float*)d_in[0];
    const float* tgtp = (const float*)d_in[1];
    // d_in[2] = patch_size (16, structure hard-coded), d_in[3] = filter_rate
    const int* filter_rate_p = (const int*)d_in[3];
    float* ws = (float*)d_ws;

    const long long total = (long long)in_sizes[0];          // B*H*W
    const int nblocks = (int)(total / (PATCH * WIDTH));      // 4096 stripes

    // ws[0] = loss_sum, ws[1] = count; ws is poisoned 0xAA -> zero it.
    hipMemsetAsync(d_ws, 0, 2 * sizeof(float), stream);

    patch_loss_kernel<<<nblocks, 256, 0, stream>>>(outp, tgtp, filter_rate_p, ws);
    finalize_kernel<<<1, 1, 0, stream>>>(ws, (float*)d_out);
}

// Round 2
// 522.374 us; speedup vs baseline: 1.0015x; 1.0015x over previous
//
#include <hip/hip_runtime.h>

// FilteredPatchLoss: B=64, H=W=1024, p=16.
// Stripe = (b, ih): 16 rows x 1024 cols = 16384 floats, 64 patches per stripe.
// One 256-thread block per stripe; thread t owns patch t/4 across all rows
// (flat float4 idx f = k*256 + t gives patch = (f&255)>>2 = t>>2).
//
// R1: batch all 32 global_load_dwordx4 into register arrays BEFORE the
// accumulate pass. R0's 32-VGPR version serialized to ~2 loads in flight
// (latency-bound, 1.55 TB/s). 32 loads in flight/wave -> BW-bound.

#define PATCH 16
#define WIDTH 1024

__global__ __launch_bounds__(256) void patch_loss_kernel(
    const float* __restrict__ outp, const float* __restrict__ tgtp,
    const int* __restrict__ filter_rate_p, float* __restrict__ ws)
{
    const int t = threadIdx.x;
    const long long base = (long long)blockIdx.x * (PATCH * WIDTH);
    const float4* op = (const float4*)(outp + base) + t;
    const float4* tp = (const float4*)(tgtp + base) + t;

    // Issue the full load burst first: 32 dwordx4 in flight per wave.
    float4 o[16], g[16];
#pragma unroll
    for (int k = 0; k < 16; ++k) o[k] = op[k * 256];
#pragma unroll
    for (int k = 0; k < 16; ++k) g[k] = tp[k * 256];

    float ts = 0.f, ls = 0.f;
#pragma unroll
    for (int k = 0; k < 16; ++k) {
        ts += (g[k].x + g[k].y) + (g[k].z + g[k].w);
        ls += (fabsf(o[k].x - g[k].x) + fabsf(o[k].y - g[k].y)) +
              (fabsf(o[k].z - g[k].z) + fabsf(o[k].w - g[k].w));
    }

    __shared__ float s_t[256];
    __shared__ float s_l[256];
    s_t[t] = ts;
    s_l[t] = ls;
    __syncthreads();

    if (t < 64) {  // exactly wave 0
        float tsum = (s_t[4*t] + s_t[4*t+1]) + (s_t[4*t+2] + s_t[4*t+3]);
        float lsum = (s_l[4*t] + s_l[4*t+1]) + (s_l[4*t+2] + s_l[4*t+3]);
        const float fr = (float)(*filter_rate_p);
        const bool mask = (tsum * (1.0f / 256.0f)) > fr;
        float loss = mask ? lsum * (1.0f / 256.0f) : 0.0f;
        float cnt  = mask ? 1.0f : 0.0f;
#pragma unroll
        for (int off = 32; off >= 1; off >>= 1) {
            loss += __shfl_down(loss, off, 64);
            cnt  += __shfl_down(cnt,  off, 64);
        }
        if (t == 0) {
            atomicAdd(&ws[0], loss);
            atomicAdd(&ws[1], cnt);
        }
    }
}

__global__ void finalize_kernel(const float* __restrict__ ws,
                                float* __restrict__ out)
{
    out[0] = ws[0] / ws[1];
}

extern "C" void kernel_launch(void* const* d_in, const int* in_sizes, int n_in,
                              void* d_out, int out_size, void* d_ws, size_t ws_size,
                              hipStream_t stream)
{
    const float* outp = (const float*)d_in[0];
    const float* tgtp = (const float*)d_in[1];
    // d_in[2] = patch_size (16, structure hard-coded), d_in[3] = filter_rate
    const int* filter_rate_p = (const int*)d_in[3];
    float* ws = (float*)d_ws;

    const long long total = (long long)in_sizes[0];          // B*H*W
    const int nblocks = (int)(total / (PATCH * WIDTH));      // 4096 stripes

    // ws[0] = loss_sum, ws[1] = count; ws is poisoned 0xAA -> zero it.
    hipMemsetAsync(d_ws, 0, 2 * sizeof(float), stream);

    patch_loss_kernel<<<nblocks, 256, 0, stream>>>(outp, tgtp, filter_rate_p, ws);
    finalize_kernel<<<1, 1, 0, stream>>>(ws, (float*)d_out);
}

// Round 3
// 508.178 us; speedup vs baseline: 1.0295x; 1.0279x over previous
//
#include <hip/hip_runtime.h>

// FilteredPatchLoss: B=64, H=W=1024, p=16.
// Stripe = (b, ih): 16 rows x 1024 cols = 16384 floats, 64 patches per stripe.
// One 256-thread block per stripe; thread t owns patch t/4 across all rows.
//
// R2: remove the global atomic funnel. R0/R1 both sat at 169 us despite
// different load structures -> shared limiter = 8192 same-cache-line
// device-scope atomicAdds (~21 ns each serialized ~= 170 us). Stage 1 now
// does ONE uncontended float2 store per block; stage 2 reduces 4096 pairs.

#define PATCH 16
#define WIDTH 1024

__global__ __launch_bounds__(256) void patch_loss_kernel(
    const float* __restrict__ outp, const float* __restrict__ tgtp,
    const int* __restrict__ filter_rate_p, float2* __restrict__ ws)
{
    const int t = threadIdx.x;
    const long long base = (long long)blockIdx.x * (PATCH * WIDTH);
    const float4* op = (const float4*)(outp + base) + t;
    const float4* tp = (const float4*)(tgtp + base) + t;

    float4 o[16], g[16];
#pragma unroll
    for (int k = 0; k < 16; ++k) o[k] = op[k * 256];
#pragma unroll
    for (int k = 0; k < 16; ++k) g[k] = tp[k * 256];

    float ts = 0.f, ls = 0.f;
#pragma unroll
    for (int k = 0; k < 16; ++k) {
        ts += (g[k].x + g[k].y) + (g[k].z + g[k].w);
        ls += (fabsf(o[k].x - g[k].x) + fabsf(o[k].y - g[k].y)) +
              (fabsf(o[k].z - g[k].z) + fabsf(o[k].w - g[k].w));
    }

    __shared__ float s_t[256];
    __shared__ float s_l[256];
    s_t[t] = ts;
    s_l[t] = ls;
    __syncthreads();

    if (t < 64) {  // exactly wave 0
        float tsum = (s_t[4*t] + s_t[4*t+1]) + (s_t[4*t+2] + s_t[4*t+3]);
        float lsum = (s_l[4*t] + s_l[4*t+1]) + (s_l[4*t+2] + s_l[4*t+3]);
        const float fr = (float)(*filter_rate_p);
        const bool mask = (tsum * (1.0f / 256.0f)) > fr;
        float loss = mask ? lsum * (1.0f / 256.0f) : 0.0f;
        float cnt  = mask ? 1.0f : 0.0f;
#pragma unroll
        for (int off = 32; off >= 1; off >>= 1) {
            loss += __shfl_down(loss, off, 64);
            cnt  += __shfl_down(cnt,  off, 64);
        }
        if (t == 0) {
            ws[blockIdx.x] = make_float2(loss, cnt);  // uncontended store
        }
    }
}

// Single block: reduce 4096 (loss, cnt) pairs and finalize.
__global__ __launch_bounds__(1024) void reduce_kernel(
    const float2* __restrict__ ws, float* __restrict__ out, int nblocks)
{
    const int t = threadIdx.x;
    float l = 0.f, c = 0.f;
    for (int i = t; i < nblocks; i += 1024) {
        float2 v = ws[i];
        l += v.x;
        c += v.y;
    }
#pragma unroll
    for (int off = 32; off >= 1; off >>= 1) {
        l += __shfl_down(l, off, 64);
        c += __shfl_down(c, off, 64);
    }
    __shared__ float sl[16], sc[16];
    if ((t & 63) == 0) { sl[t >> 6] = l; sc[t >> 6] = c; }
    __syncthreads();
    if (t < 16) {
        l = sl[t];
        c = sc[t];
#pragma unroll
        for (int off = 8; off >= 1; off >>= 1) {
            l += __shfl_down(l, off, 64);
            c += __shfl_down(c, off, 64);
        }
        if (t == 0) out[0] = l / c;
    }
}

extern "C" void kernel_launch(void* const* d_in, const int* in_sizes, int n_in,
                              void* d_out, int out_size, void* d_ws, size_t ws_size,
                              hipStream_t stream)
{
    const float* outp = (const float*)d_in[0];
    const float* tgtp = (const float*)d_in[1];
    // d_in[2] = patch_size (16, structure hard-coded), d_in[3] = filter_rate
    const int* filter_rate_p = (const int*)d_in[3];
    float2* ws = (float2*)d_ws;

    const long long total = (long long)in_sizes[0];          // B*H*W
    const int nblocks = (int)(total / (PATCH * WIDTH));      // 4096 stripes

    patch_loss_kernel<<<nblocks, 256, 0, stream>>>(outp, tgtp, filter_rate_p, ws);
    reduce_kernel<<<1, 1024, 0, stream>>>(ws, (float*)d_out, nblocks);
}